// Round 1
// baseline (2552.235 us; speedup 1.0000x reference)
//
#include <hip/hip_runtime.h>
#include <math.h>

// Problem constants (B=2, T=2048, C=1024, H=16, D=64)
#define Bn 2
#define Tn 2048
#define Cn 1024
#define Hn 16
#define Dn 64

// ---------------------------------------------------------------------------
// GEMM: C[M,N] = A[M,K] @ B[K,N] + bias[N]   (fp32, 64x64 tile, 256 threads)
// ---------------------------------------------------------------------------
__global__ __launch_bounds__(256) void gemm_bias(const float* __restrict__ A,
                                                 const float* __restrict__ B,
                                                 const float* __restrict__ bias,
                                                 float* __restrict__ C,
                                                 int M, int N, int K) {
    // TM=64, TN=64, TK=16. Pad LDS stride to 68 floats: 68*4=272 bytes == 0 mod 16
    // so every [k][4j] float4 access is 16B-aligned (ds_read_b128-friendly).
    __shared__ float As[16][68];   // As[k][m]
    __shared__ float Bs[16][68];   // Bs[k][n]

    const int tid = threadIdx.x;
    const int tx = tid & 15;       // 0..15 -> n
    const int ty = tid >> 4;       // 0..15 -> m
    const int m0 = blockIdx.y * 64;
    const int n0 = blockIdx.x * 64;

    float acc[4][4] = {};

    for (int k0 = 0; k0 < K; k0 += 16) {
        // Load A tile 64x16 (256 float4, one per thread), store transposed.
        {
            int row = tid >> 2;            // 0..63
            int cg  = (tid & 3) << 2;      // 0,4,8,12
            float4 a = *(const float4*)(A + (size_t)(m0 + row) * K + k0 + cg);
            As[cg + 0][row] = a.x;
            As[cg + 1][row] = a.y;
            As[cg + 2][row] = a.z;
            As[cg + 3][row] = a.w;
        }
        // Load B tile 16x64 (256 float4, one per thread), direct layout.
        {
            int row = tid >> 4;            // 0..15
            int cg  = (tid & 15) << 2;     // 0..60
            *(float4*)(&Bs[row][cg]) =
                *(const float4*)(B + (size_t)(k0 + row) * N + n0 + cg);
        }
        __syncthreads();

        #pragma unroll
        for (int kk = 0; kk < 16; ++kk) {
            float4 a4 = *(const float4*)(&As[kk][ty << 2]);
            float4 b4 = *(const float4*)(&Bs[kk][tx << 2]);
            float av[4] = {a4.x, a4.y, a4.z, a4.w};
            float bv[4] = {b4.x, b4.y, b4.z, b4.w};
            #pragma unroll
            for (int i = 0; i < 4; ++i)
                #pragma unroll
                for (int j = 0; j < 4; ++j)
                    acc[i][j] += av[i] * bv[j];
        }
        __syncthreads();
    }

    // Epilogue: fused bias, float4 stores.
    const int c0 = n0 + (tx << 2);
    float4 bb = *(const float4*)(bias + c0);
    #pragma unroll
    for (int i = 0; i < 4; ++i) {
        int row = m0 + (ty << 2) + i;
        float4 o;
        o.x = acc[i][0] + bb.x;
        o.y = acc[i][1] + bb.y;
        o.z = acc[i][2] + bb.z;
        o.w = acc[i][3] + bb.w;
        *(float4*)(C + (size_t)row * N + c0) = o;
    }
}

// ---------------------------------------------------------------------------
// Flash attention (causal), fp32. One 64-lane wave per (b, h, 64-query tile).
// Each lane owns one query row: Q[64] + O[64] in registers, online softmax in
// groups of 8 keys (S[8] statically indexed -> no scratch spill).
// qkv layout: [B*T, 3*C] rows; per row [3][H][D] -> q at h*D, k at C+h*D,
// v at 2C+h*D.
// ---------------------------------------------------------------------------
__global__ __launch_bounds__(64) void attn_flash(const float* __restrict__ qkv,
                                                 float* __restrict__ y) {
    // Launch largest q-tiles first (they have the most K-tiles to visit).
    const int qt   = (int)(gridDim.x - 1) - (int)blockIdx.x;  // 0..31
    const int h    = blockIdx.y;
    const int b    = blockIdx.z;
    const int lane = threadIdx.x;      // 0..63
    const int q    = qt * 64 + lane;   // global query index in T
    const float scale = 0.125f;        // 1/sqrt(64)

    // stride 68 floats: 272B == 0 mod 16 -> aligned ds_read_b128 per [k][4j]
    __shared__ float Ks[64][68];
    __shared__ float Vs[64][68];

    const float* base = qkv + (size_t)b * Tn * (3 * Cn);

    // Q row -> registers
    float Q[64];
    {
        const float* qp = base + (size_t)q * (3 * Cn) + h * Dn;
        #pragma unroll
        for (int d = 0; d < 64; d += 4) {
            float4 t = *(const float4*)(qp + d);
            Q[d] = t.x; Q[d + 1] = t.y; Q[d + 2] = t.z; Q[d + 3] = t.w;
        }
    }

    float m = -INFINITY, l = 0.f;
    float O[64];
    #pragma unroll
    for (int d = 0; d < 64; ++d) O[d] = 0.f;

    for (int kt = 0; kt <= qt; ++kt) {
        const int k0 = kt * 64;
        // Stage K and V tiles: each lane loads one K row and one V row.
        {
            const float* kp = base + (size_t)(k0 + lane) * (3 * Cn) + Cn + h * Dn;
            const float* vp = kp + Cn;
            #pragma unroll
            for (int d = 0; d < 64; d += 4) {
                *(float4*)(&Ks[lane][d]) = *(const float4*)(kp + d);
                *(float4*)(&Vs[lane][d]) = *(const float4*)(vp + d);
            }
        }
        __syncthreads();

        // Process the 64-key tile in 8 groups of 8 keys.
        for (int g = 0; g < 8; ++g) {
            const int kb = g * 8;
            float S[8];
            float mt = -INFINITY;
            #pragma unroll
            for (int kk = 0; kk < 8; ++kk) {
                const int k = kb + kk;
                float s = 0.f;
                #pragma unroll
                for (int d = 0; d < 64; d += 4) {
                    float4 kv = *(const float4*)(&Ks[k][d]);
                    s += Q[d] * kv.x;
                    s += Q[d + 1] * kv.y;
                    s += Q[d + 2] * kv.z;
                    s += Q[d + 3] * kv.w;
                }
                s *= scale;
                if (k0 + k > q) s = -INFINITY;   // causal mask
                S[kk] = s;
                mt = fmaxf(mt, s);
            }
            const float mnew = fmaxf(m, mt);
            const float corr = __expf(m - mnew);  // 0 when m == -inf
            l *= corr;
            #pragma unroll
            for (int d = 0; d < 64; ++d) O[d] *= corr;
            #pragma unroll
            for (int kk = 0; kk < 8; ++kk) {
                const int k = kb + kk;
                const float p = __expf(S[kk] - mnew);  // 0 for masked keys
                l += p;
                #pragma unroll
                for (int d = 0; d < 64; d += 4) {
                    float4 vv = *(const float4*)(&Vs[k][d]);
                    O[d]     += p * vv.x;
                    O[d + 1] += p * vv.y;
                    O[d + 2] += p * vv.z;
                    O[d + 3] += p * vv.w;
                }
            }
            m = mnew;
        }
        __syncthreads();
    }

    // Epilogue: normalize, transpose through LDS (reuse Ks), coalesced stores.
    const float inv = 1.f / l;
    #pragma unroll
    for (int d = 0; d < 64; ++d) Ks[lane][d] = O[d] * inv;
    __syncthreads();

    float* yb = y + (size_t)(b * Tn + qt * 64) * Cn + h * Dn;
    for (int r = 0; r < 64; ++r) {
        yb[(size_t)r * Cn + lane] = Ks[r][lane];
    }
}

// ---------------------------------------------------------------------------
extern "C" void kernel_launch(void* const* d_in, const int* in_sizes, int n_in,
                              void* d_out, int out_size, void* d_ws, size_t ws_size,
                              hipStream_t stream) {
    const float* x    = (const float*)d_in[0];  // [B,T,C]
    const float* Wqkv = (const float*)d_in[1];  // [C,3C]
    const float* bqkv = (const float*)d_in[2];  // [3C]
    const float* Wo   = (const float*)d_in[3];  // [C,C]
    const float* bo   = (const float*)d_in[4];  // [C]
    float* out = (float*)d_out;                 // [B,T,C] fp32

    const int M = Bn * Tn;          // 4096
    float* qkv = (float*)d_ws;                        // [4096, 3072] = 48 MB
    float* yat = qkv + (size_t)M * (3 * Cn);          // [4096, 1024] = 16 MB

    // 1) qkv = x @ Wqkv + bqkv
    {
        dim3 grid((3 * Cn) / 64, M / 64), blk(256);
        gemm_bias<<<grid, blk, 0, stream>>>(x, Wqkv, bqkv, qkv, M, 3 * Cn, Cn);
    }
    // 2) causal flash attention per (b, h, q-tile)
    {
        dim3 grid(Tn / 64, Hn, Bn), blk(64);
        attn_flash<<<grid, blk, 0, stream>>>(qkv, yat);
    }
    // 3) out = yat @ Wo + bo
    {
        dim3 grid(Cn / 64, M / 64), blk(256);
        gemm_bias<<<grid, blk, 0, stream>>>(yat, Wo, bo, out, M, Cn, Cn);
    }
}